// Round 6
// baseline (706.847 us; speedup 1.0000x reference)
//
#include <hip/hip_runtime.h>

#define BS 256
#define THR 1024
#define NBLK 128          // blocks for pair/hist/scatter passes
#define BSH 4             // 16 nodes per coarse bucket

typedef __attribute__((ext_vector_type(8))) short bf16x8;
typedef __attribute__((ext_vector_type(4))) float f32x4;

__device__ inline unsigned bfpack2(float a, float b) {
    unsigned ua = __float_as_uint(a), ub = __float_as_uint(b);
    ua = (ua + 0x7fffu + ((ua >> 16) & 1u)) >> 16;
    ub = (ub + 0x7fffu + ((ub >> 16) & 1u)) >> 16;
    return ua | (ub << 16);
}
__device__ inline float lo16(unsigned u) { return __uint_as_float(u << 16); }
__device__ inline float hi16(unsigned u) { return __uint_as_float(u & 0xffff0000u); }
__device__ inline bf16x8 pack8(float4 a, float4 b) {
    union { unsigned u[4]; bf16x8 v; } r;
    r.u[0] = bfpack2(a.x, a.y); r.u[1] = bfpack2(a.z, a.w);
    r.u[2] = bfpack2(b.x, b.y); r.u[3] = bfpack2(b.z, b.w);
    return r.v;
}

// ---------- dtype detection ----------
__global__ void k_detect(const int* __restrict__ idx, int* __restrict__ flag) {
    int l = threadIdx.x;
    int v = idx[2 * l + 1];
    unsigned long long b = __ballot(v != 0);
    if (l == 0) flag[0] = (b == 0ULL) ? 1 : 0;
}

// ---------- convert x to bf16 rows ----------
__global__ void k_xbf16(const float* __restrict__ x, unsigned* __restrict__ xb, int total8) {
    int i = blockIdx.x * BS + threadIdx.x;
    if (i >= total8) return;
    const float4 a = *(const float4*)(x + (size_t)i * 8);
    const float4 b = *(const float4*)(x + (size_t)i * 8 + 4);
    uint4 o;
    o.x = bfpack2(a.x, a.y); o.y = bfpack2(a.z, a.w);
    o.z = bfpack2(b.x, b.y); o.w = bfpack2(b.z, b.w);
    *(uint4*)(xb + (size_t)i * 4) = o;
}

// ---------- pack W1l/W1r into MFMA B-fragment order (bf16) ----------
// slot = (path*4 + jtile)*2 + kstep ; per slot 64 lanes x 8 shorts.
__global__ void k_wprep(const float* __restrict__ W1l, const float* __restrict__ W1r,
                        unsigned short* __restrict__ wfrag) {
    int lane = threadIdx.x;   // 64
    int nloc = lane & 15, quad = lane >> 4;
    for (int p = 0; p < 2; p++) {
        const float* W = p ? W1r : W1l;
        for (int jt = 0; jt < 4; jt++) {
            for (int ks = 0; ks < 2; ks++) {
                float v[8];
#pragma unroll
                for (int i = 0; i < 8; i++) {
                    int k = ks * 32 + quad * 8 + i;
                    v[i] = W[k * 64 + jt * 16 + nloc];
                }
                bf16x8 f = pack8(make_float4(v[0], v[1], v[2], v[3]),
                                 make_float4(v[4], v[5], v[6], v[7]));
                int slot = (p * 4 + jt) * 2 + ks;
                *(bf16x8*)(wfrag + ((size_t)slot * 64 + lane) * 8) = f;
            }
        }
    }
}

// ---------- pass 1: idx -> packed pairs + per-block LDS coarse histogram ----------
__global__ __launch_bounds__(1024) void k_pairs_hist(const int* __restrict__ idx,
        const int* __restrict__ flag, int* __restrict__ pk,
        int* __restrict__ hcnt, int E, int NB) {
    extern __shared__ int hist[];
    int tid = threadIdx.x;
    for (int b = tid; b < NB; b += THR) hist[b] = 0;
    __syncthreads();
    int is64 = flag[0];
    int M = (E + 1) >> 1;
    for (int c = blockIdx.x * THR + tid; c < M; c += NBLK * THR) {
        int e0 = 2 * c;
        int s0, d0, s1 = 0, d1 = 0;
        bool two = (e0 + 1) < E;
        if (is64) {
            if (two) {
                int4 sv = *(const int4*)(idx + 4L * c);
                int4 dv = *(const int4*)(idx + 2L * E + 4L * c);
                s0 = sv.x; s1 = sv.z; d0 = dv.x; d1 = dv.z;
            } else {
                s0 = idx[2L * e0]; d0 = idx[2L * E + 2L * e0];
            }
        } else {
            if (two && !(E & 1)) {
                int2 sv = *(const int2*)(idx + 2L * c);
                int2 dv = *(const int2*)(idx + (long)E + 2L * c);
                s0 = sv.x; s1 = sv.y; d0 = dv.x; d1 = dv.y;
            } else {
                s0 = idx[e0]; d0 = idx[(long)E + e0];
                if (two) { s1 = idx[e0 + 1]; d1 = idx[(long)E + e0 + 1]; }
            }
        }
        if (two) {
            *(int4*)(pk + 4L * c) = make_int4(s0, d0, s1, d1);
            atomicAdd(&hist[d0 >> BSH], 1);
            atomicAdd(&hist[d1 >> BSH], 1);
        } else {
            *(int2*)(pk + 4L * c) = make_int2(s0, d0);
            atomicAdd(&hist[d0 >> BSH], 1);
        }
    }
    __syncthreads();
    int* hrow = hcnt + (long)blockIdx.x * NB;
    for (int b = tid; b < NB; b += THR) hrow[b] = hist[b];
}

// ---------- column-wise exclusive running sums over the NBLK private hists ----------
__global__ void k_colsum(int* __restrict__ hcnt, int* __restrict__ cnt, int NB) {
    int b = blockIdx.x * BS + threadIdx.x;
    if (b >= NB) return;
    int run = 0;
#pragma unroll 16
    for (int blk = 0; blk < NBLK; blk++) {
        int v = hcnt[(long)blk * NB + b];
        hcnt[(long)blk * NB + b] = run;
        run += v;
    }
    cnt[b] = run;
}

// ---------- exclusive scan over NB bucket counts (NB <= 8192) ----------
__global__ __launch_bounds__(1024) void k_scanNB(const int* __restrict__ cnt,
        int* __restrict__ cstart, int NB, int E) {
    __shared__ int sd[1024];
    int tid = threadIdx.x;
    int base = tid * 8;
    int v[8]; int tot = 0;
#pragma unroll
    for (int j = 0; j < 8; j++) {
        v[j] = (base + j < NB) ? cnt[base + j] : 0;
        tot += v[j];
    }
    sd[tid] = tot;
    __syncthreads();
    for (int off = 1; off < 1024; off <<= 1) {
        int x = (tid >= off) ? sd[tid - off] : 0;
        __syncthreads();
        sd[tid] += x;
        __syncthreads();
    }
    int run = sd[tid] - tot;
#pragma unroll
    for (int j = 0; j < 8; j++) {
        if (base + j < NB) cstart[base + j] = run;
        run += v[j];
    }
    if (tid == 0) cstart[NB] = E;
}

// ---------- pass 2: scatter pairs into bucket-grouped pk2 (LDS cursors) ----------
__global__ __launch_bounds__(1024) void k_scatter2(const int* __restrict__ pk,
        const int* __restrict__ hcnt, const int* __restrict__ cstart,
        int* __restrict__ pk2, int E, int NB) {
    extern __shared__ int cur[];
    int tid = threadIdx.x;
    const int* hrow = hcnt + (long)blockIdx.x * NB;
    for (int b = tid; b < NB; b += THR) cur[b] = cstart[b] + hrow[b];
    __syncthreads();
    int M = (E + 1) >> 1;
    for (int c = blockIdx.x * THR + tid; c < M; c += NBLK * THR) {
        int e0 = 2 * c;
        if (e0 + 1 < E) {
            int4 p = *(const int4*)(pk + 4L * c);
            int pos0 = atomicAdd(&cur[p.y >> BSH], 1);
            *(int2*)(pk2 + 2L * pos0) = make_int2(p.x, p.y);
            int pos1 = atomicAdd(&cur[p.w >> BSH], 1);
            *(int2*)(pk2 + 2L * pos1) = make_int2(p.z, p.w);
        } else {
            int2 p = *(const int2*)(pk + 4L * c);
            int pos0 = atomicAdd(&cur[p.y >> BSH], 1);
            *(int2*)(pk2 + 2L * pos0) = make_int2(p.x, p.y);
        }
    }
}

// ---------- FUSED: per-bucket mean-agg (LDS) + MFMA layer-1 + epilogue ----------
// block = 256 threads = one bucket of 16 nodes (= one MFMA tile).
#define AST 68   // fp32 LDS row stride (16B aligned, 2-way bank alias only)
__global__ __launch_bounds__(256) void k_aggemm(
        const unsigned short* __restrict__ xb, const int* __restrict__ pk2,
        const int* __restrict__ cstart, const unsigned short* __restrict__ wfrag,
        const float* __restrict__ b1, const float* __restrict__ W2l,
        const float* __restrict__ W2r,
        float* __restrict__ sarr, float* __restrict__ tarr,
        float* __restrict__ invdeg, int n) {
    __shared__ float agg_s[16 * AST];
    __shared__ int deg_s[16];
    __shared__ float sred[4 * 16], tred[4 * 16];

    int tid = threadIdx.x;
    int b = blockIdx.x;
    // zero LDS
    for (int i = tid; i < 16 * AST; i += 256) agg_s[i] = 0.f;
    if (tid < 16) deg_s[tid] = 0;
    __syncthreads();

    int ebeg = cstart[b], eend = cstart[b + 1];
    int grp = tid >> 4, l = tid & 15;
    for (int i = ebeg + grp; i < eend; i += 16) {
        int2 pr = *(const int2*)(pk2 + 2L * i);
        uint2 v = *(const uint2*)(xb + (size_t)pr.x * 64 + l * 4);
        int dl = pr.y & 15;
        float* row = agg_s + dl * AST + l * 4;
        atomicAdd(row + 0, lo16(v.x));
        atomicAdd(row + 1, hi16(v.x));
        atomicAdd(row + 2, lo16(v.y));
        atomicAdd(row + 3, hi16(v.y));
        if (l == 0) atomicAdd(&deg_s[dl], 1);
    }
    __syncthreads();
    // normalize (exclusive ownership: thread (m,l) owns feats 4l..4l+3 of row m)
    {
        int m = grp;
        int d = deg_s[m]; if (d < 1) d = 1;
        float inv = 1.0f / (float)d;
        float* row = agg_s + m * AST + l * 4;
        row[0] *= inv; row[1] *= inv; row[2] *= inv; row[3] *= inv;
        int node = b * 16 + m;
        if (l == 0 && node < n) invdeg[node] = inv;
    }
    __syncthreads();

    // MFMA phase: wave w handles jtile w (output cols w*16 + nloc)
    int wave = tid >> 6;
    int lane = tid & 63;
    int nloc = lane & 15, quad = lane >> 4;

    // A-frags: agg (from LDS fp32 -> bf16) and x (from global bf16)
    const float* arow = agg_s + nloc * AST + quad * 8;
    bf16x8 aA0 = pack8(*(const float4*)(arow), *(const float4*)(arow + 4));
    bf16x8 aA1 = pack8(*(const float4*)(arow + 32), *(const float4*)(arow + 36));
    int node_a = b * 16 + nloc;
    int nc = node_a < n ? node_a : (n - 1);
    const unsigned short* xr = xb + (size_t)nc * 64;
    bf16x8 aX0 = *(const bf16x8*)(xr + quad * 8);
    bf16x8 aX1 = *(const bf16x8*)(xr + 32 + quad * 8);

    // B-frags from packed table: slot = (path*4 + w)*2 + ks
    const bf16x8 bL0 = *(const bf16x8*)(wfrag + ((size_t)((0 * 4 + wave) * 2 + 0) * 64 + lane) * 8);
    const bf16x8 bL1 = *(const bf16x8*)(wfrag + ((size_t)((0 * 4 + wave) * 2 + 1) * 64 + lane) * 8);
    const bf16x8 bR0 = *(const bf16x8*)(wfrag + ((size_t)((1 * 4 + wave) * 2 + 0) * 64 + lane) * 8);
    const bf16x8 bR1 = *(const bf16x8*)(wfrag + ((size_t)((1 * 4 + wave) * 2 + 1) * 64 + lane) * 8);

    f32x4 acc = (f32x4){0.f, 0.f, 0.f, 0.f};
    acc = __builtin_amdgcn_mfma_f32_16x16x32_bf16(aA0, bL0, acc, 0, 0, 0);
    acc = __builtin_amdgcn_mfma_f32_16x16x32_bf16(aA1, bL1, acc, 0, 0, 0);
    acc = __builtin_amdgcn_mfma_f32_16x16x32_bf16(aX0, bR0, acc, 0, 0, 0);
    acc = __builtin_amdgcn_mfma_f32_16x16x32_bf16(aX1, bR1, acc, 0, 0, 0);

    // epilogue: D col = nloc -> j = wave*16 + nloc ; D row = quad*4 + r -> node
    int j = wave * 16 + nloc;
    float b1v = b1[j], w2lv = W2l[j], w2rv = W2r[j];
    float sp[4], tp[4];
#pragma unroll
    for (int r = 0; r < 4; r++) {
        float h = fmaxf(acc[r] + b1v, 0.f);
        sp[r] = h * w2lv;
        tp[r] = h * w2rv;
    }
#pragma unroll
    for (int m = 1; m < 16; m <<= 1) {
#pragma unroll
        for (int r = 0; r < 4; r++) {
            sp[r] += __shfl_xor(sp[r], m);
            tp[r] += __shfl_xor(tp[r], m);
        }
    }
    if (nloc == 0) {
#pragma unroll
        for (int r = 0; r < 4; r++) {
            sred[wave * 16 + quad * 4 + r] = sp[r];
            tred[wave * 16 + quad * 4 + r] = tp[r];
        }
    }
    __syncthreads();
    if (tid < 16) {
        int node = b * 16 + tid;
        if (node < n) {
            float s = sred[tid] + sred[16 + tid] + sred[32 + tid] + sred[48 + tid];
            float t = tred[tid] + tred[16 + tid] + tred[32 + tid] + tred[48 + tid];
            sarr[node] = s;
            tarr[node] = t;
        }
    }
}

// ---------- per-bucket layer-2 mean aggregation + output ----------
__global__ __launch_bounds__(256) void k_final2(const int* __restrict__ pk2,
        const int* __restrict__ cstart, const float* __restrict__ sarr,
        const float* __restrict__ tarr, const float* __restrict__ invdeg,
        const float* __restrict__ b2, float* __restrict__ out, int n) {
    __shared__ float accr[16 * 8];
    int tid = threadIdx.x;
    int b = blockIdx.x;
    if (tid < 128) accr[tid] = 0.f;
    __syncthreads();
    int ebeg = cstart[b], eend = cstart[b + 1];
    int rep = tid & 7;
    for (int i = ebeg + tid; i < eend; i += 256) {
        int2 pr = *(const int2*)(pk2 + 2L * i);
        float s = sarr[pr.x];
        atomicAdd(&accr[(pr.y & 15) * 8 + rep], s);
    }
    __syncthreads();
    if (tid < 16) {
        int node = b * 16 + tid;
        if (node < n) {
            float a = 0.f;
#pragma unroll
            for (int r = 0; r < 8; r++) a += accr[tid * 8 + r];
            out[node] = a * invdeg[node] + b2[0] + tarr[node];
        }
    }
}

extern "C" void kernel_launch(void* const* d_in, const int* in_sizes, int n_in,
                              void* d_out, int out_size, void* d_ws, size_t ws_size,
                              hipStream_t stream) {
    const float* x   = (const float*)d_in[0];
    const int*   idx = (const int*)d_in[1];
    const float* W1l = (const float*)d_in[2];
    const float* b1  = (const float*)d_in[3];
    const float* W1r = (const float*)d_in[4];
    const float* W2l = (const float*)d_in[5];
    const float* b2  = (const float*)d_in[6];
    const float* W2r = (const float*)d_in[7];
    float* out = (float*)d_out;

    const int n = in_sizes[0] / 64;     // 100000
    const int E = in_sizes[1] / 2;      // 1600000
    const int NB = (n + 15) >> BSH;     // coarse buckets (16 nodes each)

    char* ws = (char*)d_ws;
    size_t off = 0;
    auto carve = [&](size_t bytes) {
        void* p = ws + off;
        off = (off + bytes + 255) & ~(size_t)255;
        return p;
    };
    int*   flag   = (int*)  carve(4);
    float* sarr   = (float*)carve((size_t)n * 4);
    float* tarr   = (float*)carve((size_t)n * 4);
    float* invdeg = (float*)carve((size_t)n * 4);
    int*   cnt    = (int*)  carve((size_t)NB * 4);
    int*   cstart = (int*)  carve((size_t)(NB + 1) * 4);
    int*   hcnt   = (int*)  carve((size_t)NBLK * NB * 4);
    unsigned short* wfrag = (unsigned short*)carve(16 * 64 * 8 * 2);
    int*   pk   = (int*)carve((size_t)E * 8);
    int*   pk2  = (int*)carve((size_t)E * 8);
    unsigned short* xbu = (unsigned short*)carve((size_t)n * 128);
    (void)ws_size; (void)n_in; (void)out_size;

    const int total8 = n * 64 / 8;
    const size_t ldsNB = (size_t)NB * 4;

    k_detect<<<1, 64, 0, stream>>>(idx, flag);
    k_pairs_hist<<<NBLK, THR, ldsNB, stream>>>(idx, flag, pk, hcnt, E, NB);
    k_colsum<<<(NB + BS - 1) / BS, BS, 0, stream>>>(hcnt, cnt, NB);
    k_scanNB<<<1, 1024, 0, stream>>>(cnt, cstart, NB, E);
    k_scatter2<<<NBLK, THR, ldsNB, stream>>>(pk, hcnt, cstart, pk2, E, NB);
    k_xbf16<<<(total8 + BS - 1) / BS, BS, 0, stream>>>(x, (unsigned*)xbu, total8);
    k_wprep<<<1, 64, 0, stream>>>(W1l, W1r, wfrag);
    k_aggemm<<<NB, BS, 0, stream>>>(xbu, pk2, cstart, wfrag, b1, W2l, W2r,
                                    sarr, tarr, invdeg, n);
    k_final2<<<NB, BS, 0, stream>>>(pk2, cstart, sarr, tarr, invdeg, b2, out, n);
}

// Round 7
// 213.967 us; speedup vs baseline: 3.3035x; 3.3035x over previous
//
#include <hip/hip_runtime.h>

#define BS 256
#define THR 1024
#define NBLK 128          // blocks for pair/hist/scatter passes
#define BSH 4             // 16 nodes per coarse bucket
#define AST 68            // fp32 LDS row stride (16B aligned, 2-way bank alias only)

typedef __attribute__((ext_vector_type(8))) short bf16x8;
typedef __attribute__((ext_vector_type(4))) float f32x4;

__device__ inline unsigned bfpack2(float a, float b) {
    unsigned ua = __float_as_uint(a), ub = __float_as_uint(b);
    ua = (ua + 0x7fffu + ((ua >> 16) & 1u)) >> 16;
    ub = (ub + 0x7fffu + ((ub >> 16) & 1u)) >> 16;
    return ua | (ub << 16);
}
__device__ inline float lo16(unsigned u) { return __uint_as_float(u << 16); }
__device__ inline float hi16(unsigned u) { return __uint_as_float(u & 0xffff0000u); }
__device__ inline bf16x8 pack8(float4 a, float4 b) {
    union { unsigned u[4]; bf16x8 v; } r;
    r.u[0] = bfpack2(a.x, a.y); r.u[1] = bfpack2(a.z, a.w);
    r.u[2] = bfpack2(b.x, b.y); r.u[3] = bfpack2(b.z, b.w);
    return r.v;
}

// ---------- convert x to bf16 rows ----------
__global__ void k_xbf16(const float* __restrict__ x, unsigned* __restrict__ xb, int total8) {
    int i = blockIdx.x * BS + threadIdx.x;
    if (i >= total8) return;
    const float4 a = *(const float4*)(x + (size_t)i * 8);
    const float4 b = *(const float4*)(x + (size_t)i * 8 + 4);
    uint4 o;
    o.x = bfpack2(a.x, a.y); o.y = bfpack2(a.z, a.w);
    o.z = bfpack2(b.x, b.y); o.w = bfpack2(b.z, b.w);
    *(uint4*)(xb + (size_t)i * 4) = o;
}

// ---------- pack W1l/W1r into MFMA B-fragment order (bf16) ----------
// slot = (path*4 + jtile)*2 + kstep ; per slot 64 lanes x 8 shorts.
__global__ void k_wprep(const float* __restrict__ W1l, const float* __restrict__ W1r,
                        unsigned short* __restrict__ wfrag) {
    int lane = threadIdx.x;   // 64
    int nloc = lane & 15, quad = lane >> 4;
    for (int p = 0; p < 2; p++) {
        const float* W = p ? W1r : W1l;
        for (int jt = 0; jt < 4; jt++) {
            for (int ks = 0; ks < 2; ks++) {
                float v[8];
#pragma unroll
                for (int i = 0; i < 8; i++) {
                    int k = ks * 32 + quad * 8 + i;
                    v[i] = W[k * 64 + jt * 16 + nloc];
                }
                bf16x8 f = pack8(make_float4(v[0], v[1], v[2], v[3]),
                                 make_float4(v[4], v[5], v[6], v[7]));
                int slot = (p * 4 + jt) * 2 + ks;
                *(bf16x8*)(wfrag + ((size_t)slot * 64 + lane) * 8) = f;
            }
        }
    }
}

// ---------- pass 1: idx -> packed pairs + per-block LDS coarse histogram ----------
// (int64-vs-int32 detection inlined: wave 0 ballots the odd words)
__global__ __launch_bounds__(1024) void k_pairs_hist(const int* __restrict__ idx,
        int* __restrict__ pk, int* __restrict__ hcnt, int E, int NB) {
    extern __shared__ int hist[];
    __shared__ int is64_s;
    int tid = threadIdx.x;
    for (int b = tid; b < NB; b += THR) hist[b] = 0;
    if (tid < 64) {
        int v = idx[2 * tid + 1];
        unsigned long long bl = __ballot(v != 0);
        if (tid == 0) is64_s = (bl == 0ULL) ? 1 : 0;
    }
    __syncthreads();
    int is64 = is64_s;
    int M = (E + 1) >> 1;
    for (int c = blockIdx.x * THR + tid; c < M; c += NBLK * THR) {
        int e0 = 2 * c;
        int s0, d0, s1 = 0, d1 = 0;
        bool two = (e0 + 1) < E;
        if (is64) {
            if (two) {
                int4 sv = *(const int4*)(idx + 4L * c);
                int4 dv = *(const int4*)(idx + 2L * E + 4L * c);
                s0 = sv.x; s1 = sv.z; d0 = dv.x; d1 = dv.z;
            } else {
                s0 = idx[2L * e0]; d0 = idx[2L * E + 2L * e0];
            }
        } else {
            if (two && !(E & 1)) {
                int2 sv = *(const int2*)(idx + 2L * c);
                int2 dv = *(const int2*)(idx + (long)E + 2L * c);
                s0 = sv.x; s1 = sv.y; d0 = dv.x; d1 = dv.y;
            } else {
                s0 = idx[e0]; d0 = idx[(long)E + e0];
                if (two) { s1 = idx[e0 + 1]; d1 = idx[(long)E + e0 + 1]; }
            }
        }
        if (two) {
            *(int4*)(pk + 4L * c) = make_int4(s0, d0, s1, d1);
            atomicAdd(&hist[d0 >> BSH], 1);
            atomicAdd(&hist[d1 >> BSH], 1);
        } else {
            *(int2*)(pk + 4L * c) = make_int2(s0, d0);
            atomicAdd(&hist[d0 >> BSH], 1);
        }
    }
    __syncthreads();
    int* hrow = hcnt + (long)blockIdx.x * NB;
    for (int b = tid; b < NB; b += THR) hrow[b] = hist[b];
}

// ---------- column-wise exclusive running sums over the NBLK private hists ----------
__global__ void k_colsum(int* __restrict__ hcnt, int* __restrict__ cnt, int NB) {
    int b = blockIdx.x * BS + threadIdx.x;
    if (b >= NB) return;
    int run = 0;
#pragma unroll 16
    for (int blk = 0; blk < NBLK; blk++) {
        int v = hcnt[(long)blk * NB + b];
        hcnt[(long)blk * NB + b] = run;
        run += v;
    }
    cnt[b] = run;
}

// ---------- exclusive scan over NB bucket counts (NB <= 8192) ----------
__global__ __launch_bounds__(1024) void k_scanNB(const int* __restrict__ cnt,
        int* __restrict__ cstart, int NB, int E) {
    __shared__ int sd[1024];
    int tid = threadIdx.x;
    int base = tid * 8;
    int v[8]; int tot = 0;
#pragma unroll
    for (int j = 0; j < 8; j++) {
        v[j] = (base + j < NB) ? cnt[base + j] : 0;
        tot += v[j];
    }
    sd[tid] = tot;
    __syncthreads();
    for (int off = 1; off < 1024; off <<= 1) {
        int x = (tid >= off) ? sd[tid - off] : 0;
        __syncthreads();
        sd[tid] += x;
        __syncthreads();
    }
    int run = sd[tid] - tot;
#pragma unroll
    for (int j = 0; j < 8; j++) {
        if (base + j < NB) cstart[base + j] = run;
        run += v[j];
    }
    if (tid == 0) cstart[NB] = E;
}

// ---------- pass 2: scatter pairs into bucket-grouped pk2 (LDS cursors) ----------
__global__ __launch_bounds__(1024) void k_scatter2(const int* __restrict__ pk,
        const int* __restrict__ hcnt, const int* __restrict__ cstart,
        int* __restrict__ pk2, int E, int NB) {
    extern __shared__ int cur[];
    int tid = threadIdx.x;
    const int* hrow = hcnt + (long)blockIdx.x * NB;
    for (int b = tid; b < NB; b += THR) cur[b] = cstart[b] + hrow[b];
    __syncthreads();
    int M = (E + 1) >> 1;
    for (int c = blockIdx.x * THR + tid; c < M; c += NBLK * THR) {
        int e0 = 2 * c;
        if (e0 + 1 < E) {
            int4 p = *(const int4*)(pk + 4L * c);
            int pos0 = atomicAdd(&cur[p.y >> BSH], 1);
            *(int2*)(pk2 + 2L * pos0) = make_int2(p.x, p.y);
            int pos1 = atomicAdd(&cur[p.w >> BSH], 1);
            *(int2*)(pk2 + 2L * pos1) = make_int2(p.z, p.w);
        } else {
            int2 p = *(const int2*)(pk + 4L * c);
            int pos0 = atomicAdd(&cur[p.y >> BSH], 1);
            *(int2*)(pk2 + 2L * pos0) = make_int2(p.x, p.y);
        }
    }
}

// ---------- pass 3: per-bucket node grouping -> ptr + csr ----------
__global__ __launch_bounds__(256) void k_build(const int* __restrict__ pk2,
        const int* __restrict__ cstart, int* __restrict__ ptr,
        int* __restrict__ csr, int n, int E) {
    __shared__ int h16[16], base16[16], cur16[16];
    int b = blockIdx.x;
    int tid = threadIdx.x;
    if (tid < 16) { h16[tid] = 0; cur16[tid] = 0; }
    __syncthreads();
    int ebeg = cstart[b], eend = cstart[b + 1];
    for (int i = ebeg + tid; i < eend; i += 256) {
        int d = pk2[2L * i + 1];
        atomicAdd(&h16[d & 15], 1);
    }
    __syncthreads();
    if (tid == 0) {
        int run = 0;
#pragma unroll
        for (int j = 0; j < 16; j++) { base16[j] = run; run += h16[j]; }
    }
    __syncthreads();
    if (tid < 16) {
        int node = b * 16 + tid;
        if (node < n) ptr[node] = ebeg + base16[tid];
    }
    if (b == 0 && tid == 0) ptr[n] = E;
    for (int i = ebeg + tid; i < eend; i += 256) {
        int2 p = *(const int2*)(pk2 + 2L * i);
        int ln = p.y & 15;
        int pos = base16[ln] + atomicAdd(&cur16[ln], 1);
        csr[ebeg + pos] = p.x;
    }
}

// ---------- FUSED: CSR register-walk mean-agg + MFMA layer-1 + epilogue ----------
// block = 256 threads = one bucket of 16 nodes (= one MFMA tile).
// Gather: group g (16 lanes) owns node b*16+g; lane l owns feats 4l..4l+3 in regs.
// NO atomics anywhere in the hot loop (R6 post-mortem: LDS atomic accumulate = 10x loss).
__global__ __launch_bounds__(256) void k_agg_gemm(
        const unsigned short* __restrict__ xb, const int* __restrict__ ptr,
        const int* __restrict__ csr, const unsigned short* __restrict__ wfrag,
        const float* __restrict__ b1, const float* __restrict__ W2l,
        const float* __restrict__ W2r,
        float* __restrict__ sarr, float* __restrict__ tarr, int n) {
    __shared__ float agg_s[16 * AST];
    __shared__ float sred[4 * 16], tred[4 * 16];

    int tid = threadIdx.x;
    int b = blockIdx.x;
    int grp = tid >> 4, l = tid & 15;
    int node = b * 16 + grp;

    float f0 = 0.f, f1 = 0.f, f2 = 0.f, f3 = 0.f;
    if (node < n) {
        int p0 = ptr[node], p1 = ptr[node + 1];
        const unsigned short* base = xb + l * 4;
        int e = p0;
        for (; e + 4 <= p1; e += 4) {
            int j0 = csr[e], j1 = csr[e + 1], j2 = csr[e + 2], j3 = csr[e + 3];
            uint2 v0 = *(const uint2*)(base + (size_t)j0 * 64);
            uint2 v1 = *(const uint2*)(base + (size_t)j1 * 64);
            uint2 v2 = *(const uint2*)(base + (size_t)j2 * 64);
            uint2 v3 = *(const uint2*)(base + (size_t)j3 * 64);
            f0 += lo16(v0.x) + lo16(v1.x) + lo16(v2.x) + lo16(v3.x);
            f1 += hi16(v0.x) + hi16(v1.x) + hi16(v2.x) + hi16(v3.x);
            f2 += lo16(v0.y) + lo16(v1.y) + lo16(v2.y) + lo16(v3.y);
            f3 += hi16(v0.y) + hi16(v1.y) + hi16(v2.y) + hi16(v3.y);
        }
        for (; e < p1; e++) {
            int j = csr[e];
            uint2 v = *(const uint2*)(base + (size_t)j * 64);
            f0 += lo16(v.x); f1 += hi16(v.x); f2 += lo16(v.y); f3 += hi16(v.y);
        }
        int d = p1 - p0; if (d < 1) d = 1;
        float inv = 1.0f / (float)d;
        f0 *= inv; f1 *= inv; f2 *= inv; f3 *= inv;
    }
    *(float4*)(agg_s + grp * AST + l * 4) = make_float4(f0, f1, f2, f3);
    __syncthreads();

    // MFMA phase: wave w handles jtile w (output cols w*16 + nloc)
    int wave = tid >> 6;
    int lane = tid & 63;
    int nloc = lane & 15, quad = lane >> 4;

    const float* arow = agg_s + nloc * AST + quad * 8;
    bf16x8 aA0 = pack8(*(const float4*)(arow), *(const float4*)(arow + 4));
    bf16x8 aA1 = pack8(*(const float4*)(arow + 32), *(const float4*)(arow + 36));
    int node_a = b * 16 + nloc;
    int nc = node_a < n ? node_a : (n - 1);
    const unsigned short* xr = xb + (size_t)nc * 64;
    bf16x8 aX0 = *(const bf16x8*)(xr + quad * 8);
    bf16x8 aX1 = *(const bf16x8*)(xr + 32 + quad * 8);

    const bf16x8 bL0 = *(const bf16x8*)(wfrag + ((size_t)((0 * 4 + wave) * 2 + 0) * 64 + lane) * 8);
    const bf16x8 bL1 = *(const bf16x8*)(wfrag + ((size_t)((0 * 4 + wave) * 2 + 1) * 64 + lane) * 8);
    const bf16x8 bR0 = *(const bf16x8*)(wfrag + ((size_t)((1 * 4 + wave) * 2 + 0) * 64 + lane) * 8);
    const bf16x8 bR1 = *(const bf16x8*)(wfrag + ((size_t)((1 * 4 + wave) * 2 + 1) * 64 + lane) * 8);

    f32x4 acc = (f32x4){0.f, 0.f, 0.f, 0.f};
    acc = __builtin_amdgcn_mfma_f32_16x16x32_bf16(aA0, bL0, acc, 0, 0, 0);
    acc = __builtin_amdgcn_mfma_f32_16x16x32_bf16(aA1, bL1, acc, 0, 0, 0);
    acc = __builtin_amdgcn_mfma_f32_16x16x32_bf16(aX0, bR0, acc, 0, 0, 0);
    acc = __builtin_amdgcn_mfma_f32_16x16x32_bf16(aX1, bR1, acc, 0, 0, 0);

    // epilogue: D col = nloc -> j = wave*16 + nloc ; D row = quad*4 + r -> node
    int j = wave * 16 + nloc;
    float b1v = b1[j], w2lv = W2l[j], w2rv = W2r[j];
    float sp[4], tp[4];
#pragma unroll
    for (int r = 0; r < 4; r++) {
        float h = fmaxf(acc[r] + b1v, 0.f);
        sp[r] = h * w2lv;
        tp[r] = h * w2rv;
    }
#pragma unroll
    for (int m = 1; m < 16; m <<= 1) {
#pragma unroll
        for (int r = 0; r < 4; r++) {
            sp[r] += __shfl_xor(sp[r], m);
            tp[r] += __shfl_xor(tp[r], m);
        }
    }
    if (nloc == 0) {
#pragma unroll
        for (int r = 0; r < 4; r++) {
            sred[wave * 16 + quad * 4 + r] = sp[r];
            tred[wave * 16 + quad * 4 + r] = tp[r];
        }
    }
    __syncthreads();
    if (tid < 16) {
        int nd = b * 16 + tid;
        if (nd < n) {
            sarr[nd] = sred[tid] + sred[16 + tid] + sred[32 + tid] + sred[48 + tid];
            tarr[nd] = tred[tid] + tred[16 + tid] + tred[32 + tid] + tred[48 + tid];
        }
    }
}

// ---------- layer-2 mean aggregation of scalar s + output ----------
__global__ void k_final(const int* __restrict__ ptr, const int* __restrict__ csr,
                        const float* __restrict__ sarr, const float* __restrict__ tarr,
                        const float* __restrict__ b2, float* __restrict__ out, int n) {
    int i = blockIdx.x * BS + threadIdx.x;
    if (i >= n) return;
    int p0 = ptr[i], p1 = ptr[i + 1];
    float a = 0.f;
    int e = p0;
    for (; e + 4 <= p1; e += 4) {
        int j0 = csr[e], j1 = csr[e + 1], j2 = csr[e + 2], j3 = csr[e + 3];
        a += sarr[j0] + sarr[j1] + sarr[j2] + sarr[j3];
    }
    for (; e < p1; e++) a += sarr[csr[e]];
    int d = p1 - p0; if (d < 1) d = 1;
    out[i] = a / (float)d + b2[0] + tarr[i];
}

extern "C" void kernel_launch(void* const* d_in, const int* in_sizes, int n_in,
                              void* d_out, int out_size, void* d_ws, size_t ws_size,
                              hipStream_t stream) {
    const float* x   = (const float*)d_in[0];
    const int*   idx = (const int*)d_in[1];
    const float* W1l = (const float*)d_in[2];
    const float* b1  = (const float*)d_in[3];
    const float* W1r = (const float*)d_in[4];
    const float* W2l = (const float*)d_in[5];
    const float* b2  = (const float*)d_in[6];
    const float* W2r = (const float*)d_in[7];
    float* out = (float*)d_out;

    const int n = in_sizes[0] / 64;     // 100000
    const int E = in_sizes[1] / 2;      // 1600000
    const int NB = (n + 15) >> BSH;     // coarse buckets (16 nodes each)

    char* ws = (char*)d_ws;
    size_t off = 0;
    auto carve = [&](size_t bytes) {
        void* p = ws + off;
        off = (off + bytes + 255) & ~(size_t)255;
        return p;
    };
    float* sarr   = (float*)carve((size_t)n * 4);
    float* tarr   = (float*)carve((size_t)n * 4);
    int*   ptr    = (int*)  carve((size_t)(n + 1) * 4);
    int*   csr    = (int*)  carve((size_t)E * 4);
    int*   cnt    = (int*)  carve((size_t)NB * 4);
    int*   cstart = (int*)  carve((size_t)(NB + 1) * 4);
    int*   hcnt   = (int*)  carve((size_t)NBLK * NB * 4);
    unsigned short* wfrag = (unsigned short*)carve(16 * 64 * 8 * 2);
    int*   pk   = (int*)carve((size_t)E * 8);
    int*   pk2  = (int*)carve((size_t)E * 8);
    unsigned short* xbu = (unsigned short*)carve((size_t)n * 128);
    (void)ws_size; (void)n_in; (void)out_size;

    const int nbN = (n + BS - 1) / BS;
    const int total8 = n * 64 / 8;
    const size_t ldsNB = (size_t)NB * 4;

    k_pairs_hist<<<NBLK, THR, ldsNB, stream>>>(idx, pk, hcnt, E, NB);
    k_colsum<<<(NB + BS - 1) / BS, BS, 0, stream>>>(hcnt, cnt, NB);
    k_scanNB<<<1, 1024, 0, stream>>>(cnt, cstart, NB, E);
    k_scatter2<<<NBLK, THR, ldsNB, stream>>>(pk, hcnt, cstart, pk2, E, NB);
    k_build<<<NB, BS, 0, stream>>>(pk2, cstart, ptr, csr, n, E);
    k_xbf16<<<(total8 + BS - 1) / BS, BS, 0, stream>>>(x, (unsigned*)xbu, total8);
    k_wprep<<<1, 64, 0, stream>>>(W1l, W1r, wfrag);
    k_agg_gemm<<<NB, BS, 0, stream>>>(xbu, ptr, csr, wfrag, b1, W2l, W2r,
                                      sarr, tarr, n);
    k_final<<<nbN, BS, 0, stream>>>(ptr, csr, sarr, tarr, b2, out, n);
}

// Round 8
// 198.370 us; speedup vs baseline: 3.5633x; 1.0786x over previous
//
#include <hip/hip_runtime.h>

#define BS 256
#define THR 1024
#define NBLK 128          // blocks for pair/hist/scatter passes
#define BSH 4             // 16 nodes per coarse bucket
#define AST 68            // fp32 LDS row stride (16B aligned, 2-way bank alias only)
#define CAP 1024          // max edges per bucket for LDS sort (fallback beyond)

typedef __attribute__((ext_vector_type(8))) short bf16x8;
typedef __attribute__((ext_vector_type(4))) float f32x4;

__device__ inline unsigned bfpack2(float a, float b) {
    unsigned ua = __float_as_uint(a), ub = __float_as_uint(b);
    ua = (ua + 0x7fffu + ((ua >> 16) & 1u)) >> 16;
    ub = (ub + 0x7fffu + ((ub >> 16) & 1u)) >> 16;
    return ua | (ub << 16);
}
__device__ inline float lo16(unsigned u) { return __uint_as_float(u << 16); }
__device__ inline float hi16(unsigned u) { return __uint_as_float(u & 0xffff0000u); }
__device__ inline bf16x8 pack8(float4 a, float4 b) {
    union { unsigned u[4]; bf16x8 v; } r;
    r.u[0] = bfpack2(a.x, a.y); r.u[1] = bfpack2(a.z, a.w);
    r.u[2] = bfpack2(b.x, b.y); r.u[3] = bfpack2(b.z, b.w);
    return r.v;
}

// ---------- MERGED prep: pairs+hist | x->bf16 | weight-frag pack (block-range split) ----------
__global__ __launch_bounds__(1024) void k_prep_all(const int* __restrict__ idx,
        int* __restrict__ pk, int* __restrict__ hcnt, int E, int NB,
        const float* __restrict__ x, unsigned* __restrict__ xb, int total8,
        const float* __restrict__ W1l, const float* __restrict__ W1r,
        unsigned short* __restrict__ wfrag, int xblocks) {
    extern __shared__ int hist[];
    __shared__ int is64_s;
    int tid = threadIdx.x;
    int bid = blockIdx.x;

    if (bid < NBLK) {
        // ---- pairs + per-block coarse histogram ----
        for (int b = tid; b < NB; b += THR) hist[b] = 0;
        if (tid < 64) {
            int v = idx[2 * tid + 1];
            unsigned long long bl = __ballot(v != 0);
            if (tid == 0) is64_s = (bl == 0ULL) ? 1 : 0;
        }
        __syncthreads();
        int is64 = is64_s;
        int M = (E + 1) >> 1;
        for (int c = bid * THR + tid; c < M; c += NBLK * THR) {
            int e0 = 2 * c;
            int s0, d0, s1 = 0, d1 = 0;
            bool two = (e0 + 1) < E;
            if (is64) {
                if (two) {
                    int4 sv = *(const int4*)(idx + 4L * c);
                    int4 dv = *(const int4*)(idx + 2L * E + 4L * c);
                    s0 = sv.x; s1 = sv.z; d0 = dv.x; d1 = dv.z;
                } else {
                    s0 = idx[2L * e0]; d0 = idx[2L * E + 2L * e0];
                }
            } else {
                if (two && !(E & 1)) {
                    int2 sv = *(const int2*)(idx + 2L * c);
                    int2 dv = *(const int2*)(idx + (long)E + 2L * c);
                    s0 = sv.x; s1 = sv.y; d0 = dv.x; d1 = dv.y;
                } else {
                    s0 = idx[e0]; d0 = idx[(long)E + e0];
                    if (two) { s1 = idx[e0 + 1]; d1 = idx[(long)E + e0 + 1]; }
                }
            }
            if (two) {
                *(int4*)(pk + 4L * c) = make_int4(s0, d0, s1, d1);
                atomicAdd(&hist[d0 >> BSH], 1);
                atomicAdd(&hist[d1 >> BSH], 1);
            } else {
                *(int2*)(pk + 4L * c) = make_int2(s0, d0);
                atomicAdd(&hist[d0 >> BSH], 1);
            }
        }
        __syncthreads();
        int* hrow = hcnt + (long)bid * NB;
        for (int b = tid; b < NB; b += THR) hrow[b] = hist[b];
    } else if (bid < NBLK + xblocks) {
        // ---- x -> bf16 ----
        int i = (bid - NBLK) * THR + tid;
        if (i < total8) {
            const float4 a = *(const float4*)(x + (size_t)i * 8);
            const float4 b = *(const float4*)(x + (size_t)i * 8 + 4);
            uint4 o;
            o.x = bfpack2(a.x, a.y); o.y = bfpack2(a.z, a.w);
            o.z = bfpack2(b.x, b.y); o.w = bfpack2(b.z, b.w);
            *(uint4*)(xb + (size_t)i * 4) = o;
        }
    } else {
        // ---- pack W1l/W1r into MFMA B-fragment order ----
        if (tid < 64) {
            int lane = tid;
            int nloc = lane & 15, quad = lane >> 4;
            for (int p = 0; p < 2; p++) {
                const float* W = p ? W1r : W1l;
                for (int jt = 0; jt < 4; jt++) {
                    for (int ks = 0; ks < 2; ks++) {
                        float v[8];
#pragma unroll
                        for (int i = 0; i < 8; i++) {
                            int k = ks * 32 + quad * 8 + i;
                            v[i] = W[k * 64 + jt * 16 + nloc];
                        }
                        bf16x8 f = pack8(make_float4(v[0], v[1], v[2], v[3]),
                                         make_float4(v[4], v[5], v[6], v[7]));
                        int slot = (p * 4 + jt) * 2 + ks;
                        *(bf16x8*)(wfrag + ((size_t)slot * 64 + lane) * 8) = f;
                    }
                }
            }
        }
    }
}

// ---------- column-wise exclusive running sums over the NBLK private hists ----------
__global__ void k_colsum(int* __restrict__ hcnt, int* __restrict__ cnt, int NB) {
    int b = blockIdx.x * BS + threadIdx.x;
    if (b >= NB) return;
    int run = 0;
#pragma unroll 16
    for (int blk = 0; blk < NBLK; blk++) {
        int v = hcnt[(long)blk * NB + b];
        hcnt[(long)blk * NB + b] = run;
        run += v;
    }
    cnt[b] = run;
}

// ---------- exclusive scan over NB bucket counts (NB <= 8192) ----------
__global__ __launch_bounds__(1024) void k_scanNB(const int* __restrict__ cnt,
        int* __restrict__ cstart, int NB, int E) {
    __shared__ int sd[1024];
    int tid = threadIdx.x;
    int base = tid * 8;
    int v[8]; int tot = 0;
#pragma unroll
    for (int j = 0; j < 8; j++) {
        v[j] = (base + j < NB) ? cnt[base + j] : 0;
        tot += v[j];
    }
    sd[tid] = tot;
    __syncthreads();
    for (int off = 1; off < 1024; off <<= 1) {
        int x = (tid >= off) ? sd[tid - off] : 0;
        __syncthreads();
        sd[tid] += x;
        __syncthreads();
    }
    int run = sd[tid] - tot;
#pragma unroll
    for (int j = 0; j < 8; j++) {
        if (base + j < NB) cstart[base + j] = run;
        run += v[j];
    }
    if (tid == 0) cstart[NB] = E;
}

// ---------- pass 2: scatter pairs into bucket-grouped pk2 (LDS cursors) ----------
__global__ __launch_bounds__(1024) void k_scatter2(const int* __restrict__ pk,
        const int* __restrict__ hcnt, const int* __restrict__ cstart,
        int* __restrict__ pk2, int E, int NB) {
    extern __shared__ int cur[];
    int tid = threadIdx.x;
    const int* hrow = hcnt + (long)blockIdx.x * NB;
    for (int b = tid; b < NB; b += THR) cur[b] = cstart[b] + hrow[b];
    __syncthreads();
    int M = (E + 1) >> 1;
    for (int c = blockIdx.x * THR + tid; c < M; c += NBLK * THR) {
        int e0 = 2 * c;
        if (e0 + 1 < E) {
            int4 p = *(const int4*)(pk + 4L * c);
            int pos0 = atomicAdd(&cur[p.y >> BSH], 1);
            *(int2*)(pk2 + 2L * pos0) = make_int2(p.x, p.y);
            int pos1 = atomicAdd(&cur[p.w >> BSH], 1);
            *(int2*)(pk2 + 2L * pos1) = make_int2(p.z, p.w);
        } else {
            int2 p = *(const int2*)(pk + 4L * c);
            int pos0 = atomicAdd(&cur[p.y >> BSH], 1);
            *(int2*)(pk2 + 2L * pos0) = make_int2(p.x, p.y);
        }
    }
}

// ---------- FUSED: LDS counting-sort + register-walk mean-agg + MFMA + epilogue ----------
// block = 256 threads = one bucket of 16 nodes (= one MFMA tile).
// Edge grouping done in LDS (2 int atomics/edge on 16 bins — NOT R6's 64 float atomics).
__global__ __launch_bounds__(256) void k_agg_gemm(
        const unsigned short* __restrict__ xb, const int* __restrict__ pk2,
        const int* __restrict__ cstart, const unsigned short* __restrict__ wfrag,
        const float* __restrict__ b1, const float* __restrict__ W2l,
        const float* __restrict__ W2r,
        float* __restrict__ sarr, float* __restrict__ tarr,
        float* __restrict__ invdeg, int n) {
    __shared__ int2 ebuf[CAP];
    __shared__ int srcb[CAP];
    __shared__ int h16[16], base16[16], cur16[16];
    __shared__ float agg_s[16 * AST];
    __shared__ float sred[4 * 16], tred[4 * 16];

    int tid = threadIdx.x;
    int b = blockIdx.x;
    int grp = tid >> 4, l = tid & 15;
    int node = b * 16 + grp;
    int ebeg = cstart[b], eend = cstart[b + 1], m = eend - ebeg;

    if (tid < 16) { h16[tid] = 0; cur16[tid] = 0; }
    __syncthreads();

    float f0 = 0.f, f1 = 0.f, f2 = 0.f, f3 = 0.f;
    int cnt = 0;
    const unsigned short* xbase = xb + l * 4;

    if (m <= CAP) {
        // load edges to LDS + 16-bin histogram
        for (int i = tid; i < m; i += 256) {
            int2 p = *(const int2*)(pk2 + 2L * (ebeg + i));
            ebuf[i] = p;
            atomicAdd(&h16[p.y & 15], 1);
        }
        __syncthreads();
        if (tid == 0) {
            int run = 0;
#pragma unroll
            for (int j = 0; j < 16; j++) { base16[j] = run; run += h16[j]; }
        }
        __syncthreads();
        for (int i = tid; i < m; i += 256) {
            int2 p = ebuf[i];
            int bin = p.y & 15;
            int pos = base16[bin] + atomicAdd(&cur16[bin], 1);
            srcb[pos] = p.x;
        }
        __syncthreads();
        // register walk, 8-deep MLP
        cnt = h16[grp];
        int s0 = base16[grp];
        int e = 0;
        for (; e + 8 <= cnt; e += 8) {
            int j0 = srcb[s0+e+0], j1 = srcb[s0+e+1], j2 = srcb[s0+e+2], j3 = srcb[s0+e+3];
            int j4 = srcb[s0+e+4], j5 = srcb[s0+e+5], j6 = srcb[s0+e+6], j7 = srcb[s0+e+7];
            uint2 v0 = *(const uint2*)(xbase + (size_t)j0 * 64);
            uint2 v1 = *(const uint2*)(xbase + (size_t)j1 * 64);
            uint2 v2 = *(const uint2*)(xbase + (size_t)j2 * 64);
            uint2 v3 = *(const uint2*)(xbase + (size_t)j3 * 64);
            uint2 v4 = *(const uint2*)(xbase + (size_t)j4 * 64);
            uint2 v5 = *(const uint2*)(xbase + (size_t)j5 * 64);
            uint2 v6 = *(const uint2*)(xbase + (size_t)j6 * 64);
            uint2 v7 = *(const uint2*)(xbase + (size_t)j7 * 64);
            f0 += lo16(v0.x) + lo16(v1.x) + lo16(v2.x) + lo16(v3.x)
                + lo16(v4.x) + lo16(v5.x) + lo16(v6.x) + lo16(v7.x);
            f1 += hi16(v0.x) + hi16(v1.x) + hi16(v2.x) + hi16(v3.x)
                + hi16(v4.x) + hi16(v5.x) + hi16(v6.x) + hi16(v7.x);
            f2 += lo16(v0.y) + lo16(v1.y) + lo16(v2.y) + lo16(v3.y)
                + lo16(v4.y) + lo16(v5.y) + lo16(v6.y) + lo16(v7.y);
            f3 += hi16(v0.y) + hi16(v1.y) + hi16(v2.y) + hi16(v3.y)
                + hi16(v4.y) + hi16(v5.y) + hi16(v6.y) + hi16(v7.y);
        }
        for (; e < cnt; e++) {
            int j = srcb[s0 + e];
            uint2 v = *(const uint2*)(xbase + (size_t)j * 64);
            f0 += lo16(v.x); f1 += hi16(v.x); f2 += lo16(v.y); f3 += hi16(v.y);
        }
    } else {
        // fallback (distribution-independent correctness): scan all bucket edges, filter
        for (int i = 0; i < m; i++) {
            int2 p = *(const int2*)(pk2 + 2L * (ebeg + i));
            if ((p.y & 15) == grp) {
                cnt++;
                uint2 v = *(const uint2*)(xbase + (size_t)p.x * 64);
                f0 += lo16(v.x); f1 += hi16(v.x); f2 += lo16(v.y); f3 += hi16(v.y);
            }
        }
    }
    {
        int d = cnt < 1 ? 1 : cnt;
        float inv = 1.0f / (float)d;
        f0 *= inv; f1 *= inv; f2 *= inv; f3 *= inv;
        if (l == 0 && node < n) invdeg[node] = inv;
    }
    *(float4*)(agg_s + grp * AST + l * 4) = make_float4(f0, f1, f2, f3);
    __syncthreads();

    // MFMA phase: wave w handles jtile w (output cols w*16 + nloc)
    int wave = tid >> 6;
    int lane = tid & 63;
    int nloc = lane & 15, quad = lane >> 4;

    const float* arow = agg_s + nloc * AST + quad * 8;
    bf16x8 aA0 = pack8(*(const float4*)(arow), *(const float4*)(arow + 4));
    bf16x8 aA1 = pack8(*(const float4*)(arow + 32), *(const float4*)(arow + 36));
    int node_a = b * 16 + nloc;
    int nc = node_a < n ? node_a : (n - 1);
    const unsigned short* xr = xb + (size_t)nc * 64;
    bf16x8 aX0 = *(const bf16x8*)(xr + quad * 8);
    bf16x8 aX1 = *(const bf16x8*)(xr + 32 + quad * 8);

    const bf16x8 bL0 = *(const bf16x8*)(wfrag + ((size_t)((0 * 4 + wave) * 2 + 0) * 64 + lane) * 8);
    const bf16x8 bL1 = *(const bf16x8*)(wfrag + ((size_t)((0 * 4 + wave) * 2 + 1) * 64 + lane) * 8);
    const bf16x8 bR0 = *(const bf16x8*)(wfrag + ((size_t)((1 * 4 + wave) * 2 + 0) * 64 + lane) * 8);
    const bf16x8 bR1 = *(const bf16x8*)(wfrag + ((size_t)((1 * 4 + wave) * 2 + 1) * 64 + lane) * 8);

    f32x4 acc = (f32x4){0.f, 0.f, 0.f, 0.f};
    acc = __builtin_amdgcn_mfma_f32_16x16x32_bf16(aA0, bL0, acc, 0, 0, 0);
    acc = __builtin_amdgcn_mfma_f32_16x16x32_bf16(aA1, bL1, acc, 0, 0, 0);
    acc = __builtin_amdgcn_mfma_f32_16x16x32_bf16(aX0, bR0, acc, 0, 0, 0);
    acc = __builtin_amdgcn_mfma_f32_16x16x32_bf16(aX1, bR1, acc, 0, 0, 0);

    // epilogue: D col = nloc -> j = wave*16 + nloc ; D row = quad*4 + r -> node
    int j = wave * 16 + nloc;
    float b1v = b1[j], w2lv = W2l[j], w2rv = W2r[j];
    float sp[4], tp[4];
#pragma unroll
    for (int r = 0; r < 4; r++) {
        float h = fmaxf(acc[r] + b1v, 0.f);
        sp[r] = h * w2lv;
        tp[r] = h * w2rv;
    }
#pragma unroll
    for (int mm = 1; mm < 16; mm <<= 1) {
#pragma unroll
        for (int r = 0; r < 4; r++) {
            sp[r] += __shfl_xor(sp[r], mm);
            tp[r] += __shfl_xor(tp[r], mm);
        }
    }
    if (nloc == 0) {
#pragma unroll
        for (int r = 0; r < 4; r++) {
            sred[wave * 16 + quad * 4 + r] = sp[r];
            tred[wave * 16 + quad * 4 + r] = tp[r];
        }
    }
    __syncthreads();
    if (tid < 16) {
        int nd = b * 16 + tid;
        if (nd < n) {
            sarr[nd] = sred[tid] + sred[16 + tid] + sred[32 + tid] + sred[48 + tid];
            tarr[nd] = tred[tid] + tred[16 + tid] + tred[32 + tid] + tred[48 + tid];
        }
    }
}

// ---------- per-bucket layer-2 mean aggregation + output ----------
__global__ __launch_bounds__(256) void k_final2(const int* __restrict__ pk2,
        const int* __restrict__ cstart, const float* __restrict__ sarr,
        const float* __restrict__ tarr, const float* __restrict__ invdeg,
        const float* __restrict__ b2, float* __restrict__ out, int n) {
    __shared__ float accr[16 * 8];
    int tid = threadIdx.x;
    int b = blockIdx.x;
    if (tid < 128) accr[tid] = 0.f;
    __syncthreads();
    int ebeg = cstart[b], eend = cstart[b + 1];
    int rep = tid & 7;
    for (int i = ebeg + tid; i < eend; i += 256) {
        int2 pr = *(const int2*)(pk2 + 2L * i);
        float s = sarr[pr.x];
        atomicAdd(&accr[(pr.y & 15) * 8 + rep], s);
    }
    __syncthreads();
    if (tid < 16) {
        int node = b * 16 + tid;
        if (node < n) {
            float a = 0.f;
#pragma unroll
            for (int r = 0; r < 8; r++) a += accr[tid * 8 + r];
            out[node] = a * invdeg[node] + b2[0] + tarr[node];
        }
    }
}

extern "C" void kernel_launch(void* const* d_in, const int* in_sizes, int n_in,
                              void* d_out, int out_size, void* d_ws, size_t ws_size,
                              hipStream_t stream) {
    const float* x   = (const float*)d_in[0];
    const int*   idx = (const int*)d_in[1];
    const float* W1l = (const float*)d_in[2];
    const float* b1  = (const float*)d_in[3];
    const float* W1r = (const float*)d_in[4];
    const float* W2l = (const float*)d_in[5];
    const float* b2  = (const float*)d_in[6];
    const float* W2r = (const float*)d_in[7];
    float* out = (float*)d_out;

    const int n = in_sizes[0] / 64;     // 100000
    const int E = in_sizes[1] / 2;      // 1600000
    const int NB = (n + 15) >> BSH;     // coarse buckets (16 nodes each)

    char* ws = (char*)d_ws;
    size_t off = 0;
    auto carve = [&](size_t bytes) {
        void* p = ws + off;
        off = (off + bytes + 255) & ~(size_t)255;
        return p;
    };
    float* sarr   = (float*)carve((size_t)n * 4);
    float* tarr   = (float*)carve((size_t)n * 4);
    float* invdeg = (float*)carve((size_t)n * 4);
    int*   cnt    = (int*)  carve((size_t)NB * 4);
    int*   cstart = (int*)  carve((size_t)(NB + 1) * 4);
    int*   hcnt   = (int*)  carve((size_t)NBLK * NB * 4);
    unsigned short* wfrag = (unsigned short*)carve(16 * 64 * 8 * 2);
    int*   pk   = (int*)carve((size_t)E * 8);
    int*   pk2  = (int*)carve((size_t)E * 8);
    unsigned short* xbu = (unsigned short*)carve((size_t)n * 128);
    (void)ws_size; (void)n_in; (void)out_size;

    const int total8 = n * 64 / 8;
    const int xblocks = (total8 + THR - 1) / THR;
    const size_t ldsNB = (size_t)NB * 4;

    k_prep_all<<<NBLK + xblocks + 1, THR, ldsNB, stream>>>(
        idx, pk, hcnt, E, NB, x, (unsigned*)xbu, total8, W1l, W1r, wfrag, xblocks);
    k_colsum<<<(NB + BS - 1) / BS, BS, 0, stream>>>(hcnt, cnt, NB);
    k_scanNB<<<1, 1024, 0, stream>>>(cnt, cstart, NB, E);
    k_scatter2<<<NBLK, THR, ldsNB, stream>>>(pk, hcnt, cstart, pk2, E, NB);
    k_agg_gemm<<<NB, BS, 0, stream>>>(xbu, pk2, cstart, wfrag, b1, W2l, W2r,
                                      sarr, tarr, invdeg, n);
    k_final2<<<NB, BS, 0, stream>>>(pk2, cstart, sarr, tarr, invdeg, b2, out, n);
}